// Round 1
// baseline (343.953 us; speedup 1.0000x reference)
//
#include <hip/hip_runtime.h>
#include <hip/hip_bf16.h>

#define N_PTS 12288
#define DIM   64
#define KSEL  16
#define EPS_F 1e-5f
#define XTR   24    // per-(row,chunk) survivors handed to the merge kernel
#define TSAMP 1024                 // threshold sample size (stride-12 subset)
#define TSTRIDE (N_PTS / TSAMP)    // 12
#define TMARGIN 2.0f               // covers bf16 cross-pair noise (~20 sigma)

typedef __bf16 bf16x8 __attribute__((ext_vector_type(8)));
typedef float  f32x4  __attribute__((ext_vector_type(4)));

// ---------------------------------------------------------------------------
// Kernel A: fp32 row norms sq[i], S1 = sum(sq), Sx[d] = column sums (for the
// closed-form sigma2), and a bf16 copy of coords for the MFMA screen.
// Grid 512 x 256 thr: 2048 waves, each wave strides 6 rows; lane = dim.
// ---------------------------------------------------------------------------
__global__ __launch_bounds__(256) void stats_kernel(
    const float* __restrict__ coords,
    float* __restrict__ sq,
    float* __restrict__ s1,
    float* __restrict__ sx,
    __hip_bfloat16* __restrict__ chi)
{
    __shared__ float colsh[4][64];
    const int lane = threadIdx.x & 63;
    const int wave = threadIdx.x >> 6;
    const int gw   = blockIdx.x * 4 + wave;     // 0..2047
    float colsum = 0.f, sqsum = 0.f;
    for (int r = gw; r < N_PTS; r += 2048) {
        const float x = coords[r * DIM + lane];
        chi[r * DIM + lane] = __float2bfloat16(x);
        colsum += x;
        float p = x * x;
        #pragma unroll
        for (int off = 32; off > 0; off >>= 1)
            p += __shfl_xor(p, off, 64);
        if (lane == 0) { sq[r] = p; sqsum += p; }
    }
    colsh[wave][lane] = colsum;
    __syncthreads();
    if (wave == 0) {
        const float c = colsh[0][lane] + colsh[1][lane]
                      + colsh[2][lane] + colsh[3][lane];
        atomicAdd(&sx[lane], c);
    }
    if (lane == 0) atomicAdd(s1, sqsum);
}

// Branchless insert into a descending-sorted 4-list (v[0] = max).
// Caller guarantees c < v[0].
__device__ __forceinline__ void insert4f(float (&v)[4], float c)
{
    #pragma unroll
    for (int t = 0; t < 3; ++t) {
        const bool shift = (v[t + 1] > c);
        const bool place = (!shift) && (v[t] > c);
        v[t] = shift ? v[t + 1] : (place ? c : v[t]);
    }
    if (v[3] > c) v[3] = c;
}

// ---------------------------------------------------------------------------
// Kernel T (threshold): per row, a certified upper bound on the true 16th-NN
// distance: exact 16th smallest of the pooled per-lane top-4s over a fixed
// 1024-sample (stride-12 subset, self excluded). Since pool and sample are
// subsets of the full j-set, T >= true d16 always. Block = 256 thr / 4 waves,
// 32 rows per block (same i-layout as scan); wave scans 256 samples.
// ---------------------------------------------------------------------------
__global__ __launch_bounds__(256) void thresh_kernel(
    const float* __restrict__ sq,
    const __hip_bfloat16* __restrict__ chi,
    float* __restrict__ thr)
{
    __shared__ float pool[32][64];

    const int tid  = threadIdx.x;
    const int lane = tid & 63;
    const int wave = tid >> 6;
    const int col  = lane & 15;
    const int quad = lane >> 4;
    const int ibase = (int)blockIdx.x * 32;
    const int i0 = ibase + col;
    const int i1 = ibase + 16 + col;

    const bf16x8* cp = (const bf16x8*)chi;
    const bf16x8 b00 = cp[i0 * 8 + quad], b01 = cp[i0 * 8 + quad + 4];
    const bf16x8 b10 = cp[i1 * 8 + quad], b11 = cp[i1 * 8 + quad + 4];
    const float base0 = sq[i0] + EPS_F;
    const float base1 = sq[i1] + EPS_F;

    float v0[4], v1[4];
    #pragma unroll
    for (int t = 0; t < 4; ++t) { v0[t] = 1e30f; v1[t] = 1e30f; }

    const int sw = wave * (TSAMP / 4);
    #pragma unroll 1
    for (int s = 0; s < TSAMP / 4 / 16; ++s) {
        const int s0 = sw + s * 16;
        const int arow = (s0 + col) * TSTRIDE;
        const bf16x8 a0 = cp[arow * 8 + quad];
        const bf16x8 a1 = cp[arow * 8 + quad + 4];
        f32x4 acc0 = {0.f, 0.f, 0.f, 0.f};
        acc0 = __builtin_amdgcn_mfma_f32_16x16x32_bf16(a0, b00, acc0, 0, 0, 0);
        acc0 = __builtin_amdgcn_mfma_f32_16x16x32_bf16(a1, b01, acc0, 0, 0, 0);
        f32x4 acc1 = {0.f, 0.f, 0.f, 0.f};
        acc1 = __builtin_amdgcn_mfma_f32_16x16x32_bf16(a0, b10, acc1, 0, 0, 0);
        acc1 = __builtin_amdgcn_mfma_f32_16x16x32_bf16(a1, b11, acc1, 0, 0, 0);
        #pragma unroll
        for (int r = 0; r < 4; ++r) {
            const int js = (s0 + quad * 4 + r) * TSTRIDE;
            const float sj = sq[js];
            float d2a = base0 + sj - 2.0f * acc0[r];
            float d2b = base1 + sj - 2.0f * acc1[r];
            if (js == i0) d2a = 1e30f;      // exclude self from the bound
            if (js == i1) d2b = 1e30f;
            if (d2a < v0[0]) insert4f(v0, d2a);
            if (d2b < v1[0]) insert4f(v1, d2b);
        }
    }

    // pool: 16 lanes x 4 values per row -> exact 16th smallest of the 64
    const int slot = wave * 4 + quad;
    #pragma unroll
    for (int t = 0; t < 4; ++t) {
        pool[col][slot * 4 + t]        = v0[t];
        pool[16 + col][slot * 4 + t]   = v1[t];
    }
    __syncthreads();

    #pragma unroll 1
    for (int rr = 0; rr < 8; ++rr) {
        const int row = wave * 8 + rr;
        float val = pool[row][lane];
        float T = 0.f;
        #pragma unroll 1
        for (int k = 0; k < 16; ++k) {
            float m = val;
            #pragma unroll
            for (int off = 1; off < 64; off <<= 1) {
                const float o = __shfl_xor(m, off, 64);
                m = o < m ? o : m;
            }
            if (val == m) val = 1e30f;   // dup removal keeps T an upper bound
            T = m;
        }
        if (lane == 0) thr[ibase + row] = T + TMARGIN;
    }
}

// ---------------------------------------------------------------------------
// Kernel B (scan): bf16-MFMA dist2 over one j-chunk, STATIC certified per-row
// threshold screen, survivors appended to a per-row LDS list via ds_atomic,
// per-(row,chunk) top-24 out to global ws. No sorted lists, no drains, no
// per-step shuffle chains in the hot loop. Self (j==i) is NOT filtered here;
// merge drops it (j==row -> d2=1e300).
// ---------------------------------------------------------------------------
template<int CHUNKS>
__global__ __launch_bounds__(256) void scan_kernel(
    const float* __restrict__ sq,
    const __hip_bfloat16* __restrict__ chi,
    const float* __restrict__ thr,
    unsigned* __restrict__ wsknn)            // [N][CHUNKS][XTR]
{
    // cap ~10 sigma above expected survivors (59/118/236 per row-chunk)
    constexpr int CAP = (CHUNKS == 4) ? 192 : (CHUNKS == 2) ? 320 : 448;
    constexpr int RER = CAP / 64;
    __shared__ unsigned list[32][CAP];
    __shared__ int cnt[32];

    const int tid  = threadIdx.x;
    const int lane = tid & 63;
    const int wave = tid >> 6;
    const int col  = lane & 15;
    const int quad = lane >> 4;
    const int ibase = (int)blockIdx.x * 32;
    const int i0 = ibase + col;
    const int i1 = ibase + 16 + col;

    for (int t = tid; t < 32 * CAP; t += 256)
        ((unsigned*)list)[t] = 0xFFFFFFFFu;
    if (tid < 32) cnt[tid] = 0;

    const bf16x8* cp = (const bf16x8*)chi;
    const bf16x8 b00 = cp[i0 * 8 + quad], b01 = cp[i0 * 8 + quad + 4];
    const bf16x8 b10 = cp[i1 * 8 + quad], b11 = cp[i1 * 8 + quad + 4];
    const float base0 = sq[i0] + EPS_F;
    const float base1 = sq[i1] + EPS_F;
    const float T0 = thr[i0];
    const float T1 = thr[i1];

    __syncthreads();

    const int chunk = (int)blockIdx.y;
    const int jw = chunk * (N_PTS / CHUNKS) + wave * (N_PTS / CHUNKS / 4);
    const int STEPS = N_PTS / CHUNKS / 64;

    #pragma unroll 1
    for (int s = 0; s < STEPS; ++s) {
        const int j0 = jw + s * 16;
        const int arow = j0 + col;
        const bf16x8 a0 = cp[arow * 8 + quad];
        const bf16x8 a1 = cp[arow * 8 + quad + 4];
        f32x4 acc0 = {0.f, 0.f, 0.f, 0.f};
        acc0 = __builtin_amdgcn_mfma_f32_16x16x32_bf16(a0, b00, acc0, 0, 0, 0);
        acc0 = __builtin_amdgcn_mfma_f32_16x16x32_bf16(a1, b01, acc0, 0, 0, 0);
        f32x4 acc1 = {0.f, 0.f, 0.f, 0.f};
        acc1 = __builtin_amdgcn_mfma_f32_16x16x32_bf16(a0, b10, acc1, 0, 0, 0);
        acc1 = __builtin_amdgcn_mfma_f32_16x16x32_bf16(a1, b11, acc1, 0, 0, 0);

        const float4 sqj = *(const float4*)(sq + j0 + quad * 4);
        const int    jq  = j0 + quad * 4;
        #pragma unroll
        for (int r = 0; r < 4; ++r) {
            const float sj = (r == 0) ? sqj.x : (r == 1) ? sqj.y
                           : (r == 2) ? sqj.z : sqj.w;
            const int j = jq + r;
            const float d2a = base0 + sj - 2.0f * acc0[r];
            const float d2b = base1 + sj - 2.0f * acc1[r];
            if (d2a < T0) {
                const unsigned pa = (__float_as_uint(d2a) & 0xFFFFC000u) | (unsigned)j;
                const int sl = atomicAdd(&cnt[col], 1);
                if (sl < CAP) list[col][sl] = pa;
            }
            if (d2b < T1) {
                const unsigned pb = (__float_as_uint(d2b) & 0xFFFFC000u) | (unsigned)j;
                const int sl = atomicAdd(&cnt[16 + col], 1);
                if (sl < CAP) list[16 + col][sl] = pb;
            }
        }
    }
    __syncthreads();

    // Extract the 24 smallest of each row's survivor list (wave w: rows 8w..).
    #pragma unroll 1
    for (int rr = 0; rr < 8; ++rr) {
        const int row = wave * 8 + rr;
        unsigned lv[RER];
        #pragma unroll
        for (int t = 0; t < RER; ++t) lv[t] = list[row][t * 64 + lane];
        unsigned keep = 0xFFFFFFFFu;
        #pragma unroll 1
        for (int k = 0; k < XTR; ++k) {
            unsigned m = lv[0];
            #pragma unroll
            for (int t = 1; t < RER; ++t) m = lv[t] < m ? lv[t] : m;
            #pragma unroll
            for (int off = 1; off < 64; off <<= 1) {
                const unsigned o = __shfl_xor(m, off, 64);
                m = o < m ? o : m;
            }
            if (lane == k) keep = m;
            #pragma unroll
            for (int t = 0; t < RER; ++t)        // real values unique (j embedded);
                if (lv[t] == m) lv[t] = 0xFFFFFFFFu;  // dup 0xFFFFFFFF removal is fine
        }
        if (lane < XTR)
            wsknn[((ibase + row) * CHUNKS + chunk) * XTR + lane] = keep;
    }
}

// ---------------------------------------------------------------------------
// Kernel C (merge): pool CHUNKS*24 survivors/row, top-32 by screen value,
// fp64-exact refine + rank-16 + fp64 laplacian, fp32 out. Sentinels
// (0xFFFFFFFF pads) and the diagonal (j==row) are neutralized here.
// Block 256 thr = 8 half-waves = 8 rows; grid N/8.
// ---------------------------------------------------------------------------
template<int CHUNKS>
__global__ __launch_bounds__(256) void merge_kernel(
    const float* __restrict__ coords,
    const float* __restrict__ pot,
    const float* __restrict__ s1,
    const float* __restrict__ sx,
    const unsigned* __restrict__ wsknn,
    float* __restrict__ out)
{
    constexpr int POOL = CHUNKS * XTR;
    constexpr int NF   = POOL < 32 ? POOL : 32;
    __shared__ double   s_inv_den;
    __shared__ unsigned allv[8][POOL];
    __shared__ int      finj[8][32];
    __shared__ double   refd[8][32];

    const int tid = threadIdx.x;
    const int hw  = tid >> 5;          // half-wave id = local row
    const int l   = tid & 31;
    const int row = (int)blockIdx.x * 8 + hw;

    if (tid == 0) {
        // sigma2 = mean(dist2 incl. +eps everywhere and +1e6 on the diagonal)
        double S1 = (double)s1[0], m2 = 0.0;
        for (int d = 0; d < DIM; ++d) { double t = (double)sx[d]; m2 += t * t; }
        const double NN = (double)N_PTS;
        s_inv_den = 1.0 / ((2.0 * NN * S1 - 2.0 * m2) / (NN * NN)
                           + 1e-5 + 1e6 / NN + 1e-5);
    }
    for (int t = l; t < POOL; t += 32)
        allv[hw][t] = wsknn[row * POOL + t];
    if (l < 32) finj[hw][l] = row;          // default: self -> inert slot
    __syncthreads();

    // rank-select the NF smallest (real values unique -> rank is a bijection;
    // 0xFFFFFFFF sentinels are skipped and rank above all real values)
    for (int t = l; t < POOL; t += 32) {
        const unsigned c = allv[hw][t];
        int rank = 0;
        #pragma unroll 4
        for (int m = 0; m < POOL; ++m) rank += (allv[hw][m] < c) ? 1 : 0;
        if (rank < NF && c != 0xFFFFFFFFu) finj[hw][rank] = (int)(c & 0x3FFFu);
    }
    __syncthreads();

    // fp64 refine (dot + both norms in one pass) + rank-16 + laplacian
    const double inv_den = s_inv_den;
    const int j = (l < NF) ? finj[hw][l] : row;
    const float4* xi = (const float4*)(coords + row * DIM);
    const float4* xj = (const float4*)(coords + j * DIM);
    double dot = 0.0, sqi = 0.0, sqj = 0.0;
    #pragma unroll
    for (int q = 0; q < DIM / 4; ++q) {
        const float4 a = xi[q], b = xj[q];
        dot += (double)a.x * (double)b.x + (double)a.y * (double)b.y
             + (double)a.z * (double)b.z + (double)a.w * (double)b.w;
        sqi += (double)a.x * (double)a.x + (double)a.y * (double)a.y
             + (double)a.z * (double)a.z + (double)a.w * (double)a.w;
        sqj += (double)b.x * (double)b.x + (double)b.y * (double)b.y
             + (double)b.z * (double)b.z + (double)b.w * (double)b.w;
    }
    double d2 = sqi + sqj + 1e-5 - 2.0 * dot;
    if (l >= NF || j == row) d2 = 1e300;   // pads, underfill and the diagonal
    refd[hw][l] = d2;
    __syncthreads();

    int rank = 0;
    #pragma unroll 1
    for (int m = 0; m < 32; ++m) {
        const double o = refd[hw][m];
        rank += (o < d2 || (o == d2 && m < l)) ? 1 : 0;
    }
    const double w = exp(-d2 * inv_den);
    double contrib = (rank < KSEL && l < NF && j != row)
                   ? w * ((double)pot[j] - (double)pot[row]) : 0.0;
    #pragma unroll
    for (int off = 1; off < 32; off <<= 1)
        contrib += __shfl_xor(contrib, off, 64);
    if (l == 0) out[row] = (float)contrib;
}

extern "C" void kernel_launch(void* const* d_in, const int* in_sizes, int n_in,
                              void* d_out, int out_size, void* d_ws, size_t ws_size,
                              hipStream_t stream)
{
    (void)in_sizes; (void)n_in; (void)out_size;
    const float* coords = (const float*)d_in[0];
    const float* pot    = (const float*)d_in[1];
    // d_in[2] is k (always 16, compiled in as KSEL)

    char* w = (char*)d_ws;
    float* sq = (float*)w;                             // [N_PTS]      49152 B
    float* s1 = (float*)(w + 49152);                   // [1]
    float* sx = (float*)(w + 49156);                   // [DIM]
    __hip_bfloat16* chi = (__hip_bfloat16*)(w + 49424);// [N*DIM] bf16 1.57 MB
    float* thr = (float*)(w + 1622288);                // [N_PTS]      49152 B
    unsigned* wsknn = (unsigned*)(w + 1671440);        // [N][C][XTR]

    const size_t need4 = 1671440 + (size_t)N_PTS * 4 * XTR * 4;  // 6.39 MB
    const size_t need2 = 1671440 + (size_t)N_PTS * 2 * XTR * 4;  // 4.03 MB

    hipMemsetAsync((void*)s1, 0, (1 + DIM) * sizeof(float), stream);
    stats_kernel<<<dim3(512), dim3(256), 0, stream>>>(coords, sq, s1, sx, chi);
    thresh_kernel<<<dim3(N_PTS / 32), dim3(256), 0, stream>>>(sq, chi, thr);

    if (ws_size >= need4) {
        scan_kernel<4><<<dim3(N_PTS / 32, 4), dim3(256), 0, stream>>>(sq, chi, thr, wsknn);
        merge_kernel<4><<<dim3(N_PTS / 8), dim3(256), 0, stream>>>(
            coords, pot, s1, sx, wsknn, (float*)d_out);
    } else if (ws_size >= need2) {
        scan_kernel<2><<<dim3(N_PTS / 32, 2), dim3(256), 0, stream>>>(sq, chi, thr, wsknn);
        merge_kernel<2><<<dim3(N_PTS / 8), dim3(256), 0, stream>>>(
            coords, pot, s1, sx, wsknn, (float*)d_out);
    } else {
        scan_kernel<1><<<dim3(N_PTS / 32, 1), dim3(256), 0, stream>>>(sq, chi, thr, wsknn);
        merge_kernel<1><<<dim3(N_PTS / 8), dim3(256), 0, stream>>>(
            coords, pot, s1, sx, wsknn, (float*)d_out);
    }
}

// Round 3
// 285.029 us; speedup vs baseline: 1.2067x; 1.2067x over previous
//
#include <hip/hip_runtime.h>
#include <hip/hip_bf16.h>

#define N_PTS 12288
#define DIM   64
#define KSEL  16
#define EPS_F 1e-5f
#define XTR   24    // per-(row,chunk) survivors, OLD fallback scan path
#define XTRN  24    // per-(row,chunk) survivors, NEW scan path (exact top-24)
#define TSAMP 1536                 // threshold sample size (stride-8 subset)
#define TSTRIDE (N_PTS / TSAMP)    // 8
#define TMARGIN 2.0f               // covers 2x bf16 cross-pair noise (~0.7)

typedef __bf16 bf16x8 __attribute__((ext_vector_type(8)));
typedef float  f32x4  __attribute__((ext_vector_type(4)));

// ---------------------------------------------------------------------------
// Kernel A: fp32 row norms sq[i], S1 = sum(sq), Sx[d] = column sums (for the
// closed-form sigma2), and a bf16 copy of coords for the MFMA screen.
// ---------------------------------------------------------------------------
__global__ __launch_bounds__(256) void stats_kernel(
    const float* __restrict__ coords,
    float* __restrict__ sq,
    float* __restrict__ s1,
    float* __restrict__ sx,
    __hip_bfloat16* __restrict__ chi)
{
    __shared__ float colsh[4][64];
    const int lane = threadIdx.x & 63;
    const int wave = threadIdx.x >> 6;
    const int gw   = blockIdx.x * 4 + wave;     // 0..2047
    float colsum = 0.f, sqsum = 0.f;
    for (int r = gw; r < N_PTS; r += 2048) {
        const float x = coords[r * DIM + lane];
        chi[r * DIM + lane] = __float2bfloat16(x);
        colsum += x;
        float p = x * x;
        #pragma unroll
        for (int off = 32; off > 0; off >>= 1)
            p += __shfl_xor(p, off, 64);
        if (lane == 0) { sq[r] = p; sqsum += p; }
    }
    colsh[wave][lane] = colsum;
    __syncthreads();
    if (wave == 0) {
        const float c = colsh[0][lane] + colsh[1][lane]
                      + colsh[2][lane] + colsh[3][lane];
        atomicAdd(&sx[lane], c);
    }
    if (lane == 0) atomicAdd(s1, sqsum);
}

// Branchless insert into a descending-sorted 4-list (v[0] = max).
// Caller guarantees c < v[0].
__device__ __forceinline__ void insert4f(float (&v)[4], float c)
{
    #pragma unroll
    for (int t = 0; t < 3; ++t) {
        const bool shift = (v[t + 1] > c);
        const bool place = (!shift) && (v[t] > c);
        v[t] = shift ? v[t + 1] : (place ? c : v[t]);
    }
    if (v[3] > c) v[3] = c;
}

// ---------------------------------------------------------------------------
// Kernel T (threshold): certified upper bound on the true 16th-NN distance:
// exact 16th smallest of pooled per-lane top-4s over a 1536-sample subset.
// pool-16th >= sample-16th >= full-set d16, so T = pool16 + margin certifies.
// Selection via broadcast rank (no shuffle chains, no bpermute).
// ---------------------------------------------------------------------------
__global__ __launch_bounds__(256) void thresh_kernel(
    const float* __restrict__ sq,
    const __hip_bfloat16* __restrict__ chi,
    float* __restrict__ thr)
{
    __shared__ float pool[32][64];

    const int tid  = threadIdx.x;
    const int lane = tid & 63;
    const int wave = tid >> 6;
    const int col  = lane & 15;
    const int quad = lane >> 4;
    const int ibase = (int)blockIdx.x * 32;
    const int i0 = ibase + col;
    const int i1 = ibase + 16 + col;

    const bf16x8* cp = (const bf16x8*)chi;
    const bf16x8 b00 = cp[i0 * 8 + quad], b01 = cp[i0 * 8 + quad + 4];
    const bf16x8 b10 = cp[i1 * 8 + quad], b11 = cp[i1 * 8 + quad + 4];
    const float base0 = sq[i0] + EPS_F;
    const float base1 = sq[i1] + EPS_F;

    float v0[4], v1[4];
    #pragma unroll
    for (int t = 0; t < 4; ++t) { v0[t] = 1e30f; v1[t] = 1e30f; }

    const int sw = wave * (TSAMP / 4);
    #pragma unroll 1
    for (int s = 0; s < TSAMP / 4 / 16; ++s) {
        const int s0 = sw + s * 16;
        const int arow = (s0 + col) * TSTRIDE;
        const bf16x8 a0 = cp[arow * 8 + quad];
        const bf16x8 a1 = cp[arow * 8 + quad + 4];
        f32x4 acc0 = {0.f, 0.f, 0.f, 0.f};
        acc0 = __builtin_amdgcn_mfma_f32_16x16x32_bf16(a0, b00, acc0, 0, 0, 0);
        acc0 = __builtin_amdgcn_mfma_f32_16x16x32_bf16(a1, b01, acc0, 0, 0, 0);
        f32x4 acc1 = {0.f, 0.f, 0.f, 0.f};
        acc1 = __builtin_amdgcn_mfma_f32_16x16x32_bf16(a0, b10, acc1, 0, 0, 0);
        acc1 = __builtin_amdgcn_mfma_f32_16x16x32_bf16(a1, b11, acc1, 0, 0, 0);
        #pragma unroll
        for (int r = 0; r < 4; ++r) {
            const int js = (s0 + quad * 4 + r) * TSTRIDE;
            const float sj = sq[js];
            float d2a = base0 + sj - 2.0f * acc0[r];
            float d2b = base1 + sj - 2.0f * acc1[r];
            if (js == i0) d2a = 1e30f;      // exclude self from the bound
            if (js == i1) d2b = 1e30f;
            if (d2a < v0[0]) insert4f(v0, d2a);
            if (d2b < v1[0]) insert4f(v1, d2b);
        }
    }

    // pool: 16 slots x 4 values per row -> exact 16th smallest of the 64
    const int slot = wave * 4 + quad;
    #pragma unroll
    for (int t = 0; t < 4; ++t) {
        pool[col][slot * 4 + t]      = v0[t];
        pool[16 + col][slot * 4 + t] = v1[t];
    }
    __syncthreads();

    // broadcast rank-select: lane's value's rank = #(smaller) (+tiebreak m)
    #pragma unroll 1
    for (int rr = 0; rr < 8; ++rr) {
        const int row = wave * 8 + rr;
        const float val = pool[row][lane];
        int rank = 0;
        #pragma unroll 8
        for (int m = 0; m < 64; ++m) {
            const float o = pool[row][m];
            rank += (o < val || (o == val && m < lane)) ? 1 : 0;
        }
        if (rank == 15) thr[ibase + row] = val + TMARGIN;
    }
}

// ---------------------------------------------------------------------------
// Kernel B NEW (scan): bf16-MFMA dist2, static certified threshold screen.
// Survivors -> per-lane PRIVATE LDS columns (CAPP=10, no atomics) + shared
// per-row overflow (OCAP=32; expected overflow <=2 even for lambda=8 tail
// rows, so drops are ~impossible -- this was round-2's failure at 8/16).
// Tail: prefix-compaction to dense rows + broadcast rank-select top-24.
// A-fragments register-prefetched one step ahead to hide L2 latency.
// ---------------------------------------------------------------------------
template<int CHUNKS>
__global__ __launch_bounds__(256) void scan_kernel(
    const float* __restrict__ sq,
    const __hip_bfloat16* __restrict__ chi,
    const float* __restrict__ thr,
    unsigned* __restrict__ wsknn)            // [N][CHUNKS][XTRN]
{
    constexpr int CAPP = 10;                 // private slots/lane/list
    constexpr int OCAP = 32;                 // shared overflow slots/row
    constexpr int DCAP = 16 * CAPP + OCAP;   // 192 dense slots/row
    constexpr int DPAD = DCAP + 1;           // 193: break mod-32 bank alias
    constexpr int LV   = (DCAP + 63) / 64;   // 3

    __shared__ unsigned buf[2 * CAPP * 256]; // [list*CAPP+p][tid]
    __shared__ int      cntT[2][4][4][16];   // [list][wave][quad][col]
    __shared__ unsigned dense[32 * DPAD];
    __shared__ unsigned ovf[32][OCAP];
    __shared__ int      ovcnt[32];
    __shared__ int      stot[32];

    const int tid  = threadIdx.x;
    const int lane = tid & 63;
    const int wave = tid >> 6;
    const int col  = lane & 15;
    const int quad = lane >> 4;
    const int ibase = (int)blockIdx.x * 32;
    const int i0 = ibase + col;
    const int i1 = ibase + 16 + col;

    if (tid < 32) ovcnt[tid] = 0;

    const bf16x8* cp = (const bf16x8*)chi;
    const bf16x8 b00 = cp[i0 * 8 + quad], b01 = cp[i0 * 8 + quad + 4];
    const bf16x8 b10 = cp[i1 * 8 + quad], b11 = cp[i1 * 8 + quad + 4];
    const float base0 = sq[i0] + EPS_F;
    const float base1 = sq[i1] + EPS_F;
    const float th0 = 0.5f * (thr[i0] - base0);  // pass iff acc > 0.5*sj - th
    const float th1 = 0.5f * (thr[i1] - base1);

    int c0 = 0, c1 = 0;
    __syncthreads();

    const int chunk = (int)blockIdx.y;
    const int jw = chunk * (N_PTS / CHUNKS) + wave * (N_PTS / CHUNKS / 4);
    const int STEPS = N_PTS / CHUNKS / 64;

    // prime the one-step prefetch pipeline
    bf16x8 a0 = cp[(jw + col) * 8 + quad];
    bf16x8 a1 = cp[(jw + col) * 8 + quad + 4];
    float4 sqj = *(const float4*)(sq + jw + quad * 4);

    #pragma unroll 1
    for (int s = 0; s < STEPS; ++s) {
        const int j0 = jw + s * 16;
        const int sn = (s + 1 < STEPS) ? s + 1 : s;       // clamped prefetch
        const int an = (jw + sn * 16 + col) * 8 + quad;
        const bf16x8 n0 = cp[an];
        const bf16x8 n1 = cp[an + 4];
        const float4 sqn = *(const float4*)(sq + jw + sn * 16 + quad * 4);

        f32x4 acc0 = {0.f, 0.f, 0.f, 0.f};
        acc0 = __builtin_amdgcn_mfma_f32_16x16x32_bf16(a0, b00, acc0, 0, 0, 0);
        acc0 = __builtin_amdgcn_mfma_f32_16x16x32_bf16(a1, b01, acc0, 0, 0, 0);
        f32x4 acc1 = {0.f, 0.f, 0.f, 0.f};
        acc1 = __builtin_amdgcn_mfma_f32_16x16x32_bf16(a0, b10, acc1, 0, 0, 0);
        acc1 = __builtin_amdgcn_mfma_f32_16x16x32_bf16(a1, b11, acc1, 0, 0, 0);

        const int jq = j0 + quad * 4;
        #pragma unroll
        for (int r = 0; r < 4; ++r) {
            const float sj = (r == 0) ? sqj.x : (r == 1) ? sqj.y
                           : (r == 2) ? sqj.z : sqj.w;
            const int j = jq + r;
            const float hsj = 0.5f * sj;
            // diagonal flows through (merge kills j==row)
            if (acc0[r] > hsj - th0) {
                const float d2a = (base0 + sj) - 2.0f * acc0[r];
                const unsigned pa = (__float_as_uint(d2a) & 0xFFFFC000u) | (unsigned)j;
                if (c0 < CAPP) { buf[c0 * 256 + tid] = pa; ++c0; }
                else { const int sl = atomicAdd(&ovcnt[col], 1);
                       if (sl < OCAP) ovf[col][sl] = pa; }
            }
            if (acc1[r] > hsj - th1) {
                const float d2b = (base1 + sj) - 2.0f * acc1[r];
                const unsigned pb = (__float_as_uint(d2b) & 0xFFFFC000u) | (unsigned)j;
                if (c1 < CAPP) { buf[(CAPP + c1) * 256 + tid] = pb; ++c1; }
                else { const int sl = atomicAdd(&ovcnt[16 + col], 1);
                       if (sl < OCAP) ovf[16 + col][sl] = pb; }
            }
        }
        a0 = n0; a1 = n1; sqj = sqn;
    }

    cntT[0][wave][quad][col] = c0;
    cntT[1][wave][quad][col] = c1;
    __syncthreads();

    // compaction: prefix over the row's 16 segment counts (seg = wave*4+quad)
    const int myseg = wave * 4 + quad;
    int base0c = 0, base1c = 0, tot0 = 0, tot1 = 0;
    #pragma unroll
    for (int s = 0; s < 16; ++s) {
        const int c0s = cntT[0][s >> 2][s & 3][col];
        const int c1s = cntT[1][s >> 2][s & 3][col];
        if (s < myseg) { base0c += c0s; base1c += c1s; }
        tot0 += c0s; tot1 += c1s;
    }
    for (int p = 0; p < c0; ++p)
        dense[col * DPAD + base0c + p] = buf[p * 256 + tid];
    for (int p = 0; p < c1; ++p)
        dense[(16 + col) * DPAD + base1c + p] = buf[(CAPP + p) * 256 + tid];
    if (wave == 0 && quad == 0) {            // 16 lanes: finalize both lists
        const int ov0 = ovcnt[col]      < OCAP ? ovcnt[col]      : OCAP;
        const int ov1 = ovcnt[16 + col] < OCAP ? ovcnt[16 + col] : OCAP;
        for (int o = 0; o < ov0; ++o) dense[col * DPAD + tot0 + o]        = ovf[col][o];
        for (int o = 0; o < ov1; ++o) dense[(16 + col) * DPAD + tot1 + o] = ovf[16 + col][o];
        stot[col]      = tot0 + ov0;
        stot[16 + col] = tot1 + ov1;
    }
    __syncthreads();

    // broadcast rank-select: exact top-24 per row (values unique: j embedded)
    #pragma unroll 1
    for (int rr = 0; rr < 8; ++rr) {
        const int row = wave * 8 + rr;
        const int S = stot[row];
        const unsigned* drow = dense + row * DPAD;
        unsigned lv[LV]; int rk[LV];
        #pragma unroll
        for (int t = 0; t < LV; ++t) {
            lv[t] = (t * 64 + lane < S) ? drow[t * 64 + lane] : 0xFFFFFFFFu;
            rk[t] = 0;
        }
        #pragma unroll 4
        for (int m = 0; m < S; ++m) {
            const unsigned o = drow[m];
            #pragma unroll
            for (int t = 0; t < LV; ++t) rk[t] += (o < lv[t]) ? 1 : 0;
        }
        unsigned* wrow = wsknn + ((size_t)(ibase + row) * CHUNKS + chunk) * XTRN;
        #pragma unroll
        for (int t = 0; t < LV; ++t)
            if (t * 64 + lane < S && rk[t] < XTRN) wrow[rk[t]] = lv[t];
        if (lane < XTRN && lane >= S) wrow[lane] = 0xFFFFFFFFu;
    }
}

// ---------------------------------------------------------------------------
// Kernel B OLD (fallback for small workspace): round-1 atomic-list scan,
// XTR=24 survivors/(row,chunk). Proven correct in round 1.
// ---------------------------------------------------------------------------
template<int CHUNKS>
__global__ __launch_bounds__(256) void scan_old(
    const float* __restrict__ sq,
    const __hip_bfloat16* __restrict__ chi,
    const float* __restrict__ thr,
    unsigned* __restrict__ wsknn)            // [N][CHUNKS][XTR]
{
    constexpr int CAP = (CHUNKS == 4) ? 192 : (CHUNKS == 2) ? 320 : 448;
    constexpr int RER = CAP / 64;
    __shared__ unsigned list[32][CAP];
    __shared__ int cnt[32];

    const int tid  = threadIdx.x;
    const int lane = tid & 63;
    const int wave = tid >> 6;
    const int col  = lane & 15;
    const int quad = lane >> 4;
    const int ibase = (int)blockIdx.x * 32;
    const int i0 = ibase + col;
    const int i1 = ibase + 16 + col;

    for (int t = tid; t < 32 * CAP; t += 256)
        ((unsigned*)list)[t] = 0xFFFFFFFFu;
    if (tid < 32) cnt[tid] = 0;

    const bf16x8* cp = (const bf16x8*)chi;
    const bf16x8 b00 = cp[i0 * 8 + quad], b01 = cp[i0 * 8 + quad + 4];
    const bf16x8 b10 = cp[i1 * 8 + quad], b11 = cp[i1 * 8 + quad + 4];
    const float base0 = sq[i0] + EPS_F;
    const float base1 = sq[i1] + EPS_F;
    const float T0 = thr[i0];
    const float T1 = thr[i1];

    __syncthreads();

    const int chunk = (int)blockIdx.y;
    const int jw = chunk * (N_PTS / CHUNKS) + wave * (N_PTS / CHUNKS / 4);
    const int STEPS = N_PTS / CHUNKS / 64;

    #pragma unroll 1
    for (int s = 0; s < STEPS; ++s) {
        const int j0 = jw + s * 16;
        const int arow = j0 + col;
        const bf16x8 a0 = cp[arow * 8 + quad];
        const bf16x8 a1 = cp[arow * 8 + quad + 4];
        f32x4 acc0 = {0.f, 0.f, 0.f, 0.f};
        acc0 = __builtin_amdgcn_mfma_f32_16x16x32_bf16(a0, b00, acc0, 0, 0, 0);
        acc0 = __builtin_amdgcn_mfma_f32_16x16x32_bf16(a1, b01, acc0, 0, 0, 0);
        f32x4 acc1 = {0.f, 0.f, 0.f, 0.f};
        acc1 = __builtin_amdgcn_mfma_f32_16x16x32_bf16(a0, b10, acc1, 0, 0, 0);
        acc1 = __builtin_amdgcn_mfma_f32_16x16x32_bf16(a1, b11, acc1, 0, 0, 0);

        const float4 sqj = *(const float4*)(sq + j0 + quad * 4);
        const int    jq  = j0 + quad * 4;
        #pragma unroll
        for (int r = 0; r < 4; ++r) {
            const float sj = (r == 0) ? sqj.x : (r == 1) ? sqj.y
                           : (r == 2) ? sqj.z : sqj.w;
            const int j = jq + r;
            const float d2a = base0 + sj - 2.0f * acc0[r];
            const float d2b = base1 + sj - 2.0f * acc1[r];
            if (d2a < T0) {
                const unsigned pa = (__float_as_uint(d2a) & 0xFFFFC000u) | (unsigned)j;
                const int sl = atomicAdd(&cnt[col], 1);
                if (sl < CAP) list[col][sl] = pa;
            }
            if (d2b < T1) {
                const unsigned pb = (__float_as_uint(d2b) & 0xFFFFC000u) | (unsigned)j;
                const int sl = atomicAdd(&cnt[16 + col], 1);
                if (sl < CAP) list[16 + col][sl] = pb;
            }
        }
    }
    __syncthreads();

    #pragma unroll 1
    for (int rr = 0; rr < 8; ++rr) {
        const int row = wave * 8 + rr;
        unsigned lv[RER];
        #pragma unroll
        for (int t = 0; t < RER; ++t) lv[t] = list[row][t * 64 + lane];
        unsigned keep = 0xFFFFFFFFu;
        #pragma unroll 1
        for (int k = 0; k < XTR; ++k) {
            unsigned m = lv[0];
            #pragma unroll
            for (int t = 1; t < RER; ++t) m = lv[t] < m ? lv[t] : m;
            #pragma unroll
            for (int off = 1; off < 64; off <<= 1) {
                const unsigned o = __shfl_xor(m, off, 64);
                m = o < m ? o : m;
            }
            if (lane == k) keep = m;
            #pragma unroll
            for (int t = 0; t < RER; ++t)
                if (lv[t] == m) lv[t] = 0xFFFFFFFFu;
        }
        if (lane < XTR)
            wsknn[((ibase + row) * CHUNKS + chunk) * XTR + lane] = keep;
    }
}

// ---------------------------------------------------------------------------
// Kernel C (merge): pool POOL survivors/row, broadcast rank-select top-32,
// fp64-exact refine + rank-16 + fp64 laplacian, fp32 out. Sentinels and the
// diagonal (j==row) neutralized here. Block 256 thr = 8 half-waves = 8 rows.
// ---------------------------------------------------------------------------
template<int POOL>
__global__ __launch_bounds__(256) void merge_kernel(
    const float* __restrict__ coords,
    const float* __restrict__ pot,
    const float* __restrict__ s1,
    const float* __restrict__ sx,
    const unsigned* __restrict__ wsknn,
    float* __restrict__ out)
{
    constexpr int NF = POOL < 32 ? POOL : 32;
    constexpr int CV = (POOL + 31) / 32;
    __shared__ double   s_inv_den;
    __shared__ unsigned allv[8][POOL];
    __shared__ int      finj[8][32];
    __shared__ double   refd[8][32];

    const int tid = threadIdx.x;
    const int hw  = tid >> 5;          // half-wave id = local row
    const int l   = tid & 31;
    const int row = (int)blockIdx.x * 8 + hw;

    if (tid == 0) {
        // sigma2 = mean(dist2 incl. +eps everywhere and +1e6 on the diagonal)
        double S1 = (double)s1[0], m2 = 0.0;
        for (int d = 0; d < DIM; ++d) { double t = (double)sx[d]; m2 += t * t; }
        const double NN = (double)N_PTS;
        s_inv_den = 1.0 / ((2.0 * NN * S1 - 2.0 * m2) / (NN * NN)
                           + 1e-5 + 1e6 / NN + 1e-5);
    }
    for (int t = l; t < POOL; t += 32)
        allv[hw][t] = wsknn[(size_t)row * POOL + t];
    finj[hw][l] = row;                 // default: self -> inert slot
    __syncthreads();

    // broadcast rank-select (real values unique -> rank is a bijection;
    // sentinels skipped and rank above all real values)
    unsigned cv[CV]; int rk[CV];
    #pragma unroll
    for (int t = 0; t < CV; ++t) {
        cv[t] = (t * 32 + l < POOL) ? allv[hw][t * 32 + l] : 0xFFFFFFFFu;
        rk[t] = 0;
    }
    #pragma unroll 4
    for (int m = 0; m < POOL; ++m) {
        const unsigned o = allv[hw][m];
        #pragma unroll
        for (int t = 0; t < CV; ++t) rk[t] += (o < cv[t]) ? 1 : 0;
    }
    #pragma unroll
    for (int t = 0; t < CV; ++t)
        if (rk[t] < NF && cv[t] != 0xFFFFFFFFu)
            finj[hw][rk[t]] = (int)(cv[t] & 0x3FFFu);
    __syncthreads();

    // fp64 refine (dot + both norms in one pass) + rank-16 + laplacian
    const double inv_den = s_inv_den;
    const int j = (l < NF) ? finj[hw][l] : row;
    const float4* xi = (const float4*)(coords + row * DIM);
    const float4* xj = (const float4*)(coords + j * DIM);
    double dot = 0.0, sqi = 0.0, sqj = 0.0;
    #pragma unroll
    for (int q = 0; q < DIM / 4; ++q) {
        const float4 a = xi[q], b = xj[q];
        dot += (double)a.x * (double)b.x + (double)a.y * (double)b.y
             + (double)a.z * (double)b.z + (double)a.w * (double)b.w;
        sqi += (double)a.x * (double)a.x + (double)a.y * (double)a.y
             + (double)a.z * (double)a.z + (double)a.w * (double)a.w;
        sqj += (double)b.x * (double)b.x + (double)b.y * (double)b.y
             + (double)b.z * (double)b.z + (double)b.w * (double)b.w;
    }
    double d2 = sqi + sqj + 1e-5 - 2.0 * dot;
    if (l >= NF || j == row) d2 = 1e300;   // pads, underfill and the diagonal
    refd[hw][l] = d2;
    __syncthreads();

    int rank = 0;
    #pragma unroll 1
    for (int m = 0; m < 32; ++m) {
        const double o = refd[hw][m];
        rank += (o < d2 || (o == d2 && m < l)) ? 1 : 0;
    }
    const double w = exp(-d2 * inv_den);
    double contrib = (rank < KSEL && l < NF && j != row)
                   ? w * ((double)pot[j] - (double)pot[row]) : 0.0;
    #pragma unroll
    for (int off = 1; off < 32; off <<= 1)
        contrib += __shfl_xor(contrib, off, 64);
    if (l == 0) out[row] = (float)contrib;
}

extern "C" void kernel_launch(void* const* d_in, const int* in_sizes, int n_in,
                              void* d_out, int out_size, void* d_ws, size_t ws_size,
                              hipStream_t stream)
{
    (void)in_sizes; (void)n_in; (void)out_size;
    const float* coords = (const float*)d_in[0];
    const float* pot    = (const float*)d_in[1];
    // d_in[2] is k (always 16, compiled in as KSEL)

    char* w = (char*)d_ws;
    float* sq = (float*)w;                             // [N_PTS]      49152 B
    float* s1 = (float*)(w + 49152);                   // [1]
    float* sx = (float*)(w + 49156);                   // [DIM]
    __hip_bfloat16* chi = (__hip_bfloat16*)(w + 49424);// [N*DIM] bf16 1.57 MB
    float* thr = (float*)(w + 1622288);                // [N_PTS]      49152 B
    unsigned* wsknn = (unsigned*)(w + 1671440);

    const size_t need_new = 1671440 + (size_t)N_PTS * 4 * XTRN * 4; // 6.39 MB
    const size_t need2    = 1671440 + (size_t)N_PTS * 2 * XTR  * 4; // 4.03 MB

    hipMemsetAsync((void*)s1, 0, (1 + DIM) * sizeof(float), stream);
    stats_kernel<<<dim3(512), dim3(256), 0, stream>>>(coords, sq, s1, sx, chi);
    thresh_kernel<<<dim3(N_PTS / 32), dim3(256), 0, stream>>>(sq, chi, thr);

    if (ws_size >= need_new) {
        scan_kernel<4><<<dim3(N_PTS / 32, 4), dim3(256), 0, stream>>>(sq, chi, thr, wsknn);
        merge_kernel<4 * XTRN><<<dim3(N_PTS / 8), dim3(256), 0, stream>>>(
            coords, pot, s1, sx, wsknn, (float*)d_out);
    } else if (ws_size >= need2) {
        scan_old<2><<<dim3(N_PTS / 32, 2), dim3(256), 0, stream>>>(sq, chi, thr, wsknn);
        merge_kernel<2 * XTR><<<dim3(N_PTS / 8), dim3(256), 0, stream>>>(
            coords, pot, s1, sx, wsknn, (float*)d_out);
    } else {
        scan_old<1><<<dim3(N_PTS / 32, 1), dim3(256), 0, stream>>>(sq, chi, thr, wsknn);
        merge_kernel<1 * XTR><<<dim3(N_PTS / 8), dim3(256), 0, stream>>>(
            coords, pot, s1, sx, wsknn, (float*)d_out);
    }
}